// Round 5
// baseline (34.641 us; speedup 1.0000x reference)
//
#include <hip/hip_runtime.h>
#include <math.h>

#define NB 16384

// Batch-independent constants staged in LDS (uniform broadcast reads).
struct SConsts {
  float MrT[8][9];  // transpose of Mlist[i][:3,:3], row-major
  float mp[8][3];   // Mlist[i][:3,3]
  float A[7][6];    // screw axes
  float Gd[7][6];   // [Ixx,Iyy,Izz,m,m,m]
  float X7p[3];     // p of adjoint(trans_inv(Mlist[7])); its R is MrT[7]
  float g[3];
  float ftip[6];
};

// Block = 64 threads = ONE wave; cross-lane LDS dependencies within a wave
// are satisfied by program order (validated r4: passed with identical absmax).
__device__ __forceinline__ void syncw() {
  __builtin_amdgcn_sched_barrier(0);
  __builtin_amdgcn_wave_barrier();
  __builtin_amdgcn_sched_barrier(0);
}

__device__ __forceinline__ float dot6(const float* a, const float* b) {
  return a[0]*b[0]+a[1]*b[1]+a[2]*b[2]+a[3]*b[3]+a[4]*b[4]+a[5]*b[5];
}

// exp6 with native sin/cos/sqrt/rcp (1-2 ulp; threshold 0.4 >> effect).
__device__ __forceinline__ void exp6_dev(float wx, float wy, float wz,
                                         float vx, float vy, float vz,
                                         float R[9], float p[3]) {
  float th2 = wx*wx + wy*wy + wz*wz;
  float th  = __builtin_amdgcn_sqrtf(th2);
  bool sm = th < 1e-10f;
  float ths = sm ? 1.0f : th;
  float inv = __builtin_amdgcn_rcpf(ths);
  float ux = wx*inv, uy = wy*inv, uz = wz*inv;
  float s = __sinf(th);
  float c = __cosf(th);
  float omc = 1.0f - c;
  float r00 = c + omc*ux*ux;
  float r01 = omc*ux*uy - s*uz;
  float r02 = omc*ux*uz + s*uy;
  float r10 = omc*uy*ux + s*uz;
  float r11 = c + omc*uy*uy;
  float r12 = omc*uy*uz - s*ux;
  float r20 = omc*uz*ux - s*uy;
  float r21 = omc*uz*uy + s*ux;
  float r22 = c + omc*uz*uz;
  float k1 = omc*inv, k2 = (th - s)*inv;
  float cx = uy*vz - uz*vy, cy = uz*vx - ux*vz, cz = ux*vy - uy*vx;
  float udv = ux*vx + uy*vy + uz*vz;
  float px = vx + k1*cx + k2*(ux*udv - vx);
  float py = vy + k1*cy + k2*(uy*udv - vy);
  float pz = vz + k1*cz + k2*(uz*udv - vz);
  R[0]=sm?1.f:r00; R[1]=sm?0.f:r01; R[2]=sm?0.f:r02;
  R[3]=sm?0.f:r10; R[4]=sm?1.f:r11; R[5]=sm?0.f:r12;
  R[6]=sm?0.f:r20; R[7]=sm?0.f:r21; R[8]=sm?1.f:r22;
  p[0]=sm?vx:px; p[1]=sm?vy:py; p[2]=sm?vz:pz;
}

// Adjoint apply: out = Ad(R,p) * in, in = (w,v). top = Rw; bot = p x (Rw) + Rv.
__device__ __forceinline__ void Xapply(const float* R, const float* p,
                                       const float in[6], float out[6]) {
  float a = R[0]*in[0]+R[1]*in[1]+R[2]*in[2];
  float b = R[3]*in[0]+R[4]*in[1]+R[5]*in[2];
  float c = R[6]*in[0]+R[7]*in[1]+R[8]*in[2];
  float d = R[0]*in[3]+R[1]*in[4]+R[2]*in[5];
  float e = R[3]*in[3]+R[4]*in[4]+R[5]*in[5];
  float f = R[6]*in[3]+R[7]*in[4]+R[8]*in[5];
  out[0]=a; out[1]=b; out[2]=c;
  out[3] = p[1]*c - p[2]*b + d;
  out[4] = p[2]*a - p[0]*c + e;
  out[5] = p[0]*b - p[1]*a + f;
}

// 8 lanes per element. Roles sub=0..6: mass-matrix column j=sub (dq=0, ddq=e_j,
// g=0, ftip=0). Role sub=7: bias torque h (real dq, ddq=0, real g, ftip).
// J-formulation: fwd pass stores J_k,sub = Vd_k; columns become dot products
// col[i] = sum_k Fb[k].J_ki (lane j: M[i][j]; lane 7: h_i) -- no backward pass.
extern "C" __global__ void __launch_bounds__(64, 2)
arm_kernel(const float* __restrict__ state, const float* __restrict__ torque,
           const float* __restrict__ Mp, const float* __restrict__ Ain,
           const float* __restrict__ Gp, const float* __restrict__ grav,
           const float* __restrict__ ftip_in, float* __restrict__ out)
{
  __shared__ SConsts C;
  __shared__ float XL[8][100];      // per element: 7 joints x (R 9 + p 3)
  __shared__ float CL[8][68];       // per element: column gather, CL[e][k*8+sub]
  __shared__ float JL[8*7*7*8];     // J_ki: [e][k][i][8 floats (6 used)]
  __shared__ float TD[8][8];        // tip dot per column
  const int t = threadIdx.x;

  // Cooperative constant staging.
  {
    int i = t >> 3;
    #pragma unroll
    for (int kk = (t & 7); kk < 12; kk += 8) {
      if (kk < 9) {
        int r = kk / 3, c = kk - 3*(kk/3);
        C.MrT[i][c*3 + r] = Mp[i*16 + r*4 + c];
      } else {
        int r = kk - 9;
        C.mp[i][r] = Mp[i*16 + r*4 + 3];
      }
    }
    if (t < 42) {
      int i2 = t / 6, k = t - 6*(t/6);
      C.A[i2][k] = Ain[t];
      C.Gd[i2][k] = (k < 3) ? Gp[i2*4 + k] : Gp[i2*4 + 3];
    }
    if (t < 3) C.g[t] = grav[t];
    if (t < 6) C.ftip[t] = ftip_in[t];
  }
  syncw();
  if (t < 3)
    C.X7p[t] = -(C.MrT[7][t*3+0]*C.mp[7][0] + C.MrT[7][t*3+1]*C.mp[7][1] + C.MrT[7][t*3+2]*C.mp[7][2]);
  syncw();

  const int sub = t & 7;
  const int e   = t >> 3;
  const int b   = blockIdx.x * 8 + e;
  const int subc = (sub < 7) ? sub : 6;   // clamp for lane 7's own-joint scalars

  float dq0[7], tau[7], dqs[7];
  #pragma unroll
  for (int k = 0; k < 7; ++k) {
    dq0[k] = state[b*14 + 7 + k];
    tau[k] = torque[b*7 + k] * 50.0f;
    dqs[k] = dq0[k];
  }
  float q0s  = state[b*14 + subc];
  float dq0s = dq0[0];
  #pragma unroll
  for (int k = 1; k < 7; ++k) dq0s = (subc == k) ? dq0[k] : dq0s;

  float qss = q0s, dqss = dq0s;
  float accqs = 0.0f, accdqs = 0.0f;
  float a[7];
  const float gm = (sub == 7) ? 1.0f : 0.0f;

  #pragma unroll 1
  for (int stage = 0; stage < 4; ++stage) {
    syncw();   // XL/JL safe to overwrite (same-wave DS program order)
    if (sub < 7) {
      float Re[9], pe[3];
      exp6_dev(-C.A[sub][0]*qss, -C.A[sub][1]*qss, -C.A[sub][2]*qss,
               -C.A[sub][3]*qss, -C.A[sub][4]*qss, -C.A[sub][5]*qss, Re, pe);
      float Xr[12];
      #pragma unroll
      for (int r = 0; r < 3; ++r) {
        #pragma unroll
        for (int c = 0; c < 3; ++c)
          Xr[r*3+c] = Re[r*3+0]*C.MrT[sub][0+c] + Re[r*3+1]*C.MrT[sub][3+c] + Re[r*3+2]*C.MrT[sub][6+c];
      }
      #pragma unroll
      for (int r = 0; r < 3; ++r)
        Xr[9+r] = pe[r] - (Xr[r*3+0]*C.mp[sub][0] + Xr[r*3+1]*C.mp[sub][1] + Xr[r*3+2]*C.mp[sub][2]);
      float4* dst = (float4*)&XL[e][sub*12];
      dst[0] = make_float4(Xr[0],Xr[1],Xr[2],Xr[3]);
      dst[1] = make_float4(Xr[4],Xr[5],Xr[6],Xr[7]);
      dst[2] = make_float4(Xr[8],Xr[9],Xr[10],Xr[11]);
    }
    syncw();

    // ---- generalized forward pass; stores J_k,sub = Vd_k to LDS ----
    float V[6] = {0,0,0,0,0,0};
    float Vd[6];
    Vd[0]=0.0f; Vd[1]=0.0f; Vd[2]=0.0f;
    Vd[3] = -gm*C.g[0]; Vd[4] = -gm*C.g[1]; Vd[5] = -gm*C.g[2];
    float Fb[7][6];
    #pragma unroll
    for (int i = 0; i < 7; ++i) {
      const float4* sx = (const float4*)&XL[e][i*12];
      float4 x0 = sx[0], x1 = sx[1], x2 = sx[2];
      float Xr[12] = {x0.x,x0.y,x0.z,x0.w, x1.x,x1.y,x1.z,x1.w, x2.x,x2.y,x2.z,x2.w};
      float dqi  = (sub == 7) ? dqs[i] : 0.0f;
      float ddqi = (sub == i) ? 1.0f : 0.0f;
      float tv[6];
      Xapply(Xr, Xr+9, V, tv);
      #pragma unroll
      for (int k = 0; k < 6; ++k) V[k] = tv[k] + C.A[i][k]*dqi;
      Xapply(Xr, Xr+9, Vd, tv);
      float wx=V[0],wy=V[1],wz=V[2],vx=V[3],vy=V[4],vz=V[5];
      float ax=C.A[i][0],ay=C.A[i][1],az=C.A[i][2];
      float bx=C.A[i][3],by=C.A[i][4],bz=C.A[i][5];
      Vd[0] = tv[0] + ax*ddqi + (wy*az - wz*ay)*dqi;
      Vd[1] = tv[1] + ay*ddqi + (wz*ax - wx*az)*dqi;
      Vd[2] = tv[2] + az*ddqi + (wx*ay - wy*ax)*dqi;
      Vd[3] = tv[3] + bx*ddqi + (vy*az - vz*ay + wy*bz - wz*by)*dqi;
      Vd[4] = tv[4] + by*ddqi + (vz*ax - vx*az + wz*bx - wx*bz)*dqi;
      Vd[5] = tv[5] + bz*ddqi + (vx*ay - vy*ax + wx*by - wy*bx)*dqi;
      // J store: lane sub<7 owns column sub; i-th step gives J_{i,sub}.
      if (sub < 7) {
        float* jp = &JL[((e*7 + i)*7 + sub)*8];
        *(float4*)jp = make_float4(Vd[0], Vd[1], Vd[2], Vd[3]);
        *(float2*)(jp + 4) = make_float2(Vd[4], Vd[5]);
      }
      float g0=C.Gd[i][0], g1=C.Gd[i][1], g2=C.Gd[i][2], m=C.Gd[i][3];
      float Gt0=g0*wx, Gt1=g1*wy, Gt2=g2*wz;
      float Gb0=m*vx,  Gb1=m*vy,  Gb2=m*vz;
      // For unit lanes (V=0): Fb[i] = G*J_{i,sub} exactly (ad-terms vanish).
      Fb[i][0] = g0*Vd[0] + (wy*Gt2 - wz*Gt1) + (vy*Gb2 - vz*Gb1);
      Fb[i][1] = g1*Vd[1] + (wz*Gt0 - wx*Gt2) + (vz*Gb0 - vx*Gb2);
      Fb[i][2] = g2*Vd[2] + (wx*Gt1 - wy*Gt0) + (vx*Gb1 - vy*Gb0);
      Fb[i][3] = m*Vd[3] + (wy*Gb2 - wz*Gb1);
      Fb[i][4] = m*Vd[4] + (wz*Gb0 - wx*Gb2);
      Fb[i][5] = m*Vd[5] + (wx*Gb1 - wy*Gb0);
    }
    // Tip term: td = ftip . (X7 * J_{6,sub})  (one Xapply through tip adjoint).
    {
      float jt[6];
      Xapply(C.MrT[7], C.X7p, Vd, jt);
      float td = dot6(jt, C.ftip);
      if (sub < 7) TD[e][sub] = td;
    }
    syncw();

    // ---- columns as dot products: col[i] = sum_{k>=i} Fb[k] . J_ki ----
    // Lane j: col[i] = M[i][j] (k<j terms are exact zeros via Fb).
    // Lane 7: col[i] = h_i (plus tip term below).
    float col[7] = {0,0,0,0,0,0,0};
    #pragma unroll
    for (int k = 0; k < 7; ++k) {
      #pragma unroll
      for (int i = 0; i <= k; ++i) {
        const float* jp = &JL[((e*7 + k)*7 + i)*8];
        float4 j0 = *(const float4*)jp;
        float2 j1 = *(const float2*)(jp + 4);
        col[i] += Fb[k][0]*j0.x + Fb[k][1]*j0.y + Fb[k][2]*j0.z
                + Fb[k][3]*j0.w + Fb[k][4]*j1.x + Fb[k][5]*j1.y;
      }
    }
    #pragma unroll
    for (int i = 0; i < 7; ++i) col[i] += gm * TD[e][i];

    // ---- gather full M + rhs via LDS ----
    #pragma unroll
    for (int k = 0; k < 7; ++k) CL[e][k*8 + sub] = col[k];
    syncw();
    float Mm[7][7], rhs[7];
    #pragma unroll
    for (int i = 0; i < 7; ++i) {
      const float4* rp = (const float4*)&CL[e][i*8];
      float4 r0 = rp[0], r1 = rp[1];
      Mm[i][0]=r0.x; Mm[i][1]=r0.y; Mm[i][2]=r0.z; Mm[i][3]=r0.w;
      Mm[i][4]=r1.x; Mm[i][5]=r1.y; Mm[i][6]=r1.z;
      rhs[i] = tau[i] - r1.w;
    }

    // ---- solve M a = rhs (SPD, no pivot); pivot reciprocals via v_rcp ----
    float invd[7];
    #pragma unroll
    for (int k = 0; k < 7; ++k) {
      invd[k] = __builtin_amdgcn_rcpf(Mm[k][k]);
      #pragma unroll
      for (int i2 = k+1; i2 < 7; ++i2) {
        float f = Mm[i2][k] * invd[k];
        #pragma unroll
        for (int c2 = k+1; c2 < 7; ++c2) Mm[i2][c2] -= f * Mm[k][c2];
        rhs[i2] -= f * rhs[k];
      }
    }
    #pragma unroll
    for (int i2 = 6; i2 >= 0; --i2) {
      float s = rhs[i2];
      #pragma unroll
      for (int c2 = i2+1; c2 < 7; ++c2) s -= Mm[i2][c2] * a[c2];
      a[i2] = s * invd[i2];
    }

    // ---- RK4 accumulate / advance (own-joint scalars) ----
    float a_own = a[0];
    #pragma unroll
    for (int k = 1; k < 7; ++k) a_own = (subc == k) ? a[k] : a_own;
    float w = (stage == 1 || stage == 2) ? 2.0f : 1.0f;
    accqs  += w*dqss;
    accdqs += w*a_own;
    if (stage < 3) {
      float cc = (stage == 2) ? 0.1f : 0.05f;
      qss  = q0s + cc*dqss;
      dqss = dq0s + cc*a_own;
      #pragma unroll
      for (int k = 0; k < 7; ++k) dqs[k] = dq0[k] + cc*a[k];
    }
  }

  const float c6 = (float)(0.1/6.0);
  const float PI_F = 3.14159265358979323846f;
  const float TWO_PI_F = 6.28318530717958647692f;
  const float INV_TWO_PI_F = 0.15915494309189535f;
  float q1 = q0s  + c6*accqs;
  float d1 = dq0s + c6*accdqs;
  float x = q1 + PI_F;
  float n = floorf(x * INV_TWO_PI_F);
  float y = fmaf(n, -TWO_PI_F, x);
  y = (y < 0.0f) ? y + TWO_PI_F : y;
  y = (y >= TWO_PI_F) ? y - TWO_PI_F : y;
  float qw_own  = y - PI_F;
  float dqw_own = fminf(fmaxf(d1, -20.0f), 20.0f);
  if (sub < 7) {
    out[b*14 + sub]     = qw_own;
    out[b*14 + 7 + sub] = dqw_own;
  }

  // ---- FK: lane sub<7 builds L_sub = M_sub * exp6(A q); translation chain. ----
  syncw();
  if (sub < 7) {
    float Re[9], pe[3];
    exp6_dev(C.A[sub][0]*qw_own, C.A[sub][1]*qw_own, C.A[sub][2]*qw_own,
             C.A[sub][3]*qw_own, C.A[sub][4]*qw_own, C.A[sub][5]*qw_own, Re, pe);
    float L[12];
    #pragma unroll
    for (int r = 0; r < 3; ++r) {
      #pragma unroll
      for (int c = 0; c < 3; ++c)   // Mr[r][k] = MrT[k*3+r]
        L[r*3+c] = C.MrT[sub][0*3+r]*Re[0*3+c] + C.MrT[sub][1*3+r]*Re[1*3+c] + C.MrT[sub][2*3+r]*Re[2*3+c];
      L[9+r] = C.MrT[sub][0*3+r]*pe[0] + C.MrT[sub][1*3+r]*pe[1] + C.MrT[sub][2*3+r]*pe[2] + C.mp[sub][r];
    }
    float4* dst = (float4*)&XL[e][sub*12];
    dst[0] = make_float4(L[0],L[1],L[2],L[3]);
    dst[1] = make_float4(L[4],L[5],L[6],L[7]);
    dst[2] = make_float4(L[8],L[9],L[10],L[11]);
  }
  syncw();
  float v0 = C.mp[7][0], v1 = C.mp[7][1], v2 = C.mp[7][2];
  #pragma unroll
  for (int i = 6; i >= 0; --i) {
    const float4* sx = (const float4*)&XL[e][i*12];
    float4 x0 = sx[0], x1 = sx[1], x2 = sx[2];
    float n0 = x0.x*v0 + x0.y*v1 + x0.z*v2 + x2.y;
    float n1 = x0.w*v0 + x1.x*v1 + x1.y*v2 + x2.z;
    float n2 = x1.z*v0 + x1.w*v1 + x2.x*v2 + x2.w;
    v0 = n0; v1 = n1; v2 = n2;
  }
  {
    float ev = v0;
    ev = (sub == 1) ? v1 : ev;
    ev = (sub == 2) ? v2 : ev;
    if (sub < 3) out[NB*14 + b*3 + sub] = ev;
  }
}

extern "C" void kernel_launch(void* const* d_in, const int* in_sizes, int n_in,
                              void* d_out, int out_size, void* d_ws, size_t ws_size,
                              hipStream_t stream) {
  const float* state  = (const float*)d_in[0];
  const float* torque = (const float*)d_in[1];
  const float* Mp     = (const float*)d_in[2];
  const float* Ain    = (const float*)d_in[3];
  const float* Gp     = (const float*)d_in[4];
  const float* grav   = (const float*)d_in[5];
  const float* ftip   = (const float*)d_in[6];
  float* out = (float*)d_out;
  hipLaunchKernelGGL(arm_kernel, dim3(NB/8), dim3(64), 0, stream,
                     state, torque, Mp, Ain, Gp, grav, ftip, out);
}

// Round 6
// 33.773 us; speedup vs baseline: 1.0257x; 1.0257x over previous
//
#include <hip/hip_runtime.h>
#include <math.h>

#define NB 16384

// Batch-independent constants staged in LDS (uniform broadcast reads).
struct SConsts {
  float MrT[8][9];  // transpose of Mlist[i][:3,:3], row-major
  float mp[8][3];   // Mlist[i][:3,3]
  float A[7][6];    // screw axes
  float Gd[7][6];   // [Ixx,Iyy,Izz,m,m,m]
  float X7p[3];     // p of adjoint(trans_inv(Mlist[7])); its R is MrT[7]
  float g[3];
  float ftip[6];
};

// Block = 64 threads = ONE wave; cross-lane LDS deps within a wave are
// satisfied by LDS program order (validated r3/r4). Compile-time fence only.
__device__ __forceinline__ void syncw() {
  __builtin_amdgcn_sched_barrier(0);
  __builtin_amdgcn_wave_barrier();
  __builtin_amdgcn_sched_barrier(0);
}

__device__ __forceinline__ float dot6(const float* a, const float* b) {
  return a[0]*b[0]+a[1]*b[1]+a[2]*b[2]+a[3]*b[3]+a[4]*b[4]+a[5]*b[5];
}

// exp6 with native sin/cos/sqrt/rcp (1-2 ulp; threshold 0.4 >> effect).
__device__ __forceinline__ void exp6_dev(float wx, float wy, float wz,
                                         float vx, float vy, float vz,
                                         float R[9], float p[3]) {
  float th2 = wx*wx + wy*wy + wz*wz;
  float th  = __builtin_amdgcn_sqrtf(th2);
  bool sm = th < 1e-10f;
  float ths = sm ? 1.0f : th;
  float inv = __builtin_amdgcn_rcpf(ths);
  float ux = wx*inv, uy = wy*inv, uz = wz*inv;
  float s = __sinf(th);
  float c = __cosf(th);
  float omc = 1.0f - c;
  float r00 = c + omc*ux*ux;
  float r01 = omc*ux*uy - s*uz;
  float r02 = omc*ux*uz + s*uy;
  float r10 = omc*uy*ux + s*uz;
  float r11 = c + omc*uy*uy;
  float r12 = omc*uy*uz - s*ux;
  float r20 = omc*uz*ux - s*uy;
  float r21 = omc*uz*uy + s*ux;
  float r22 = c + omc*uz*uz;
  float k1 = omc*inv, k2 = (th - s)*inv;
  float cx = uy*vz - uz*vy, cy = uz*vx - ux*vz, cz = ux*vy - uy*vx;
  float udv = ux*vx + uy*vy + uz*vz;
  float px = vx + k1*cx + k2*(ux*udv - vx);
  float py = vy + k1*cy + k2*(uy*udv - vy);
  float pz = vz + k1*cz + k2*(uz*udv - vz);
  R[0]=sm?1.f:r00; R[1]=sm?0.f:r01; R[2]=sm?0.f:r02;
  R[3]=sm?0.f:r10; R[4]=sm?1.f:r11; R[5]=sm?0.f:r12;
  R[6]=sm?0.f:r20; R[7]=sm?0.f:r21; R[8]=sm?1.f:r22;
  p[0]=sm?vx:px; p[1]=sm?vy:py; p[2]=sm?vz:pz;
}

__device__ __forceinline__ void Xapply(const float* R, const float* p,
                                       const float in[6], float out[6]) {
  float a = R[0]*in[0]+R[1]*in[1]+R[2]*in[2];
  float b = R[3]*in[0]+R[4]*in[1]+R[5]*in[2];
  float c = R[6]*in[0]+R[7]*in[1]+R[8]*in[2];
  float d = R[0]*in[3]+R[1]*in[4]+R[2]*in[5];
  float e = R[3]*in[3]+R[4]*in[4]+R[5]*in[5];
  float f = R[6]*in[3]+R[7]*in[4]+R[8]*in[5];
  out[0]=a; out[1]=b; out[2]=c;
  out[3] = p[1]*c - p[2]*b + d;
  out[4] = p[2]*a - p[0]*c + e;
  out[5] = p[0]*b - p[1]*a + f;
}

__device__ __forceinline__ void XTapply(const float* R, const float* p,
                                        const float in[6], float out[6]) {
  float fx=in[3], fy=in[4], fz=in[5];
  float tx = in[0] - (p[1]*fz - p[2]*fy);
  float ty = in[1] - (p[2]*fx - p[0]*fz);
  float tz = in[2] - (p[0]*fy - p[1]*fx);
  out[0] = R[0]*tx + R[3]*ty + R[6]*tz;
  out[1] = R[1]*tx + R[4]*ty + R[7]*tz;
  out[2] = R[2]*tx + R[5]*ty + R[8]*tz;
  out[3] = R[0]*fx + R[3]*fy + R[6]*fz;
  out[4] = R[1]*fx + R[4]*fy + R[7]*fz;
  out[5] = R[2]*fx + R[5]*fy + R[8]*fz;
}

// Build joint-sub adjoint X = Ad(exp6(-A_sub q) @ trans_inv(M_sub)) -> XL row.
__device__ __forceinline__ void build_X(const SConsts& C, int sub, float q,
                                        float* XLe) {
  float Re[9], pe[3];
  exp6_dev(-C.A[sub][0]*q, -C.A[sub][1]*q, -C.A[sub][2]*q,
           -C.A[sub][3]*q, -C.A[sub][4]*q, -C.A[sub][5]*q, Re, pe);
  float Xr[12];
  #pragma unroll
  for (int r = 0; r < 3; ++r) {
    #pragma unroll
    for (int c = 0; c < 3; ++c)
      Xr[r*3+c] = Re[r*3+0]*C.MrT[sub][0+c] + Re[r*3+1]*C.MrT[sub][3+c] + Re[r*3+2]*C.MrT[sub][6+c];
  }
  #pragma unroll
  for (int r = 0; r < 3; ++r)
    Xr[9+r] = pe[r] - (Xr[r*3+0]*C.mp[sub][0] + Xr[r*3+1]*C.mp[sub][1] + Xr[r*3+2]*C.mp[sub][2]);
  float4* dst = (float4*)XLe;
  dst[0] = make_float4(Xr[0],Xr[1],Xr[2],Xr[3]);
  dst[1] = make_float4(Xr[4],Xr[5],Xr[6],Xr[7]);
  dst[2] = make_float4(Xr[8],Xr[9],Xr[10],Xr[11]);
}

// Generalized RNEA (r4 math): role sub<7 = unit column, sub==7 = bias (gm=1).
__device__ __forceinline__ void rnea_pass(const SConsts& C, const float* XLe,
                                          const float dqs[7], int sub, float gm,
                                          float col[7]) {
  float V[6] = {0,0,0,0,0,0};
  float Vd[6];
  Vd[0]=0.0f; Vd[1]=0.0f; Vd[2]=0.0f;
  Vd[3] = -gm*C.g[0]; Vd[4] = -gm*C.g[1]; Vd[5] = -gm*C.g[2];
  float Fb[7][6];
  #pragma unroll
  for (int i = 0; i < 7; ++i) {
    const float4* sx = (const float4*)&XLe[i*12];
    float4 x0 = sx[0], x1 = sx[1], x2 = sx[2];
    float Xr[12] = {x0.x,x0.y,x0.z,x0.w, x1.x,x1.y,x1.z,x1.w, x2.x,x2.y,x2.z,x2.w};
    float dqi  = (sub == 7) ? dqs[i] : 0.0f;
    float ddqi = (sub == i) ? 1.0f : 0.0f;
    float tv[6];
    Xapply(Xr, Xr+9, V, tv);
    #pragma unroll
    for (int k = 0; k < 6; ++k) V[k] = tv[k] + C.A[i][k]*dqi;
    Xapply(Xr, Xr+9, Vd, tv);
    float wx=V[0],wy=V[1],wz=V[2],vx=V[3],vy=V[4],vz=V[5];
    float ax=C.A[i][0],ay=C.A[i][1],az=C.A[i][2];
    float bx=C.A[i][3],by=C.A[i][4],bz=C.A[i][5];
    Vd[0] = tv[0] + ax*ddqi + (wy*az - wz*ay)*dqi;
    Vd[1] = tv[1] + ay*ddqi + (wz*ax - wx*az)*dqi;
    Vd[2] = tv[2] + az*ddqi + (wx*ay - wy*ax)*dqi;
    Vd[3] = tv[3] + bx*ddqi + (vy*az - vz*ay + wy*bz - wz*by)*dqi;
    Vd[4] = tv[4] + by*ddqi + (vz*ax - vx*az + wz*bx - wx*bz)*dqi;
    Vd[5] = tv[5] + bz*ddqi + (vx*ay - vy*ax + wx*by - wy*bx)*dqi;
    float g0=C.Gd[i][0], g1=C.Gd[i][1], g2=C.Gd[i][2], m=C.Gd[i][3];
    float Gt0=g0*wx, Gt1=g1*wy, Gt2=g2*wz;
    float Gb0=m*vx,  Gb1=m*vy,  Gb2=m*vz;
    Fb[i][0] = g0*Vd[0] + (wy*Gt2 - wz*Gt1) + (vy*Gb2 - vz*Gb1);
    Fb[i][1] = g1*Vd[1] + (wz*Gt0 - wx*Gt2) + (vz*Gb0 - vx*Gb2);
    Fb[i][2] = g2*Vd[2] + (wx*Gt1 - wy*Gt0) + (vx*Gb1 - vy*Gb0);
    Fb[i][3] = m*Vd[3] + (wy*Gb2 - wz*Gb1);
    Fb[i][4] = m*Vd[4] + (wz*Gb0 - wx*Gb2);
    Fb[i][5] = m*Vd[5] + (wx*Gb1 - wy*Gb0);
  }
  float F[6];
  #pragma unroll
  for (int k = 0; k < 6; ++k) F[k] = gm*C.ftip[k];
  #pragma unroll
  for (int i = 6; i >= 0; --i) {
    float tv[6];
    if (i == 6) {
      XTapply(C.MrT[7], C.X7p, F, tv);
    } else {
      const float4* sx = (const float4*)&XLe[(i+1)*12];
      float4 x0 = sx[0], x1 = sx[1], x2 = sx[2];
      float Xr[12] = {x0.x,x0.y,x0.z,x0.w, x1.x,x1.y,x1.z,x1.w, x2.x,x2.y,x2.z,x2.w};
      XTapply(Xr, Xr+9, F, tv);
    }
    #pragma unroll
    for (int k = 0; k < 6; ++k) F[k] = tv[k] + Fb[i][k];
    col[i] = dot6(F, C.A[i]);
  }
}

// SPD 7x7 solve, no pivot, rcp pivots.
__device__ __forceinline__ void solve7(float Mm[7][7], float rhs[7], float a[7]) {
  float invd[7];
  #pragma unroll
  for (int k = 0; k < 7; ++k) {
    invd[k] = __builtin_amdgcn_rcpf(Mm[k][k]);
    #pragma unroll
    for (int i2 = k+1; i2 < 7; ++i2) {
      float f = Mm[i2][k] * invd[k];
      #pragma unroll
      for (int c2 = k+1; c2 < 7; ++c2) Mm[i2][c2] -= f * Mm[k][c2];
      rhs[i2] -= f * rhs[k];
    }
  }
  #pragma unroll
  for (int i2 = 6; i2 >= 0; --i2) {
    float s = rhs[i2];
    #pragma unroll
    for (int c2 = i2+1; c2 < 7; ++c2) s -= Mm[i2][c2] * a[c2];
    a[i2] = s * invd[i2];
  }
}

// 8 lanes per role-group; each group serves TWO elements (A,B) -> per-wave ILP.
// Waves: 16384/16 per block * ... grid = 1024 blocks of 64 = 1024 waves (1/SIMD),
// each carrying 2 independent element streams the compiler interleaves.
extern "C" __global__ void __launch_bounds__(64, 1)
arm_kernel(const float* __restrict__ state, const float* __restrict__ torque,
           const float* __restrict__ Mp, const float* __restrict__ Ain,
           const float* __restrict__ Gp, const float* __restrict__ grav,
           const float* __restrict__ ftip_in, float* __restrict__ out)
{
  __shared__ SConsts C;
  __shared__ float XL[16][100];  // per element: 7 joints x 12, stride 100
  __shared__ float CL[16][68];   // per element: column gather [k*8+sub]
  const int t = threadIdx.x;

  // Cooperative constant staging.
  {
    int i = t >> 3;
    #pragma unroll
    for (int kk = (t & 7); kk < 12; kk += 8) {
      if (kk < 9) {
        int r = kk / 3, c = kk - 3*(kk/3);
        C.MrT[i][c*3 + r] = Mp[i*16 + r*4 + c];
      } else {
        int r = kk - 9;
        C.mp[i][r] = Mp[i*16 + r*4 + 3];
      }
    }
    if (t < 42) {
      int i2 = t / 6, k = t - 6*(t/6);
      C.A[i2][k] = Ain[t];
      C.Gd[i2][k] = (k < 3) ? Gp[i2*4 + k] : Gp[i2*4 + 3];
    }
    if (t < 3) C.g[t] = grav[t];
    if (t < 6) C.ftip[t] = ftip_in[t];
  }
  syncw();
  if (t < 3)
    C.X7p[t] = -(C.MrT[7][t*3+0]*C.mp[7][0] + C.MrT[7][t*3+1]*C.mp[7][1] + C.MrT[7][t*3+2]*C.mp[7][2]);

  const int sub = t & 7;
  const int g   = t >> 3;
  const int eA  = g*2, eB = g*2 + 1;
  const int bA  = blockIdx.x * 16 + eA;
  const int bB  = bA + 1;
  const int subc = (sub < 7) ? sub : 6;

  float dq0A[7], tauA[7], dqsA[7], dq0B[7], tauB[7], dqsB[7];
  #pragma unroll
  for (int k = 0; k < 7; ++k) {
    dq0A[k] = state[bA*14 + 7 + k];
    tauA[k] = torque[bA*7 + k] * 50.0f;
    dqsA[k] = dq0A[k];
    dq0B[k] = state[bB*14 + 7 + k];
    tauB[k] = torque[bB*7 + k] * 50.0f;
    dqsB[k] = dq0B[k];
  }
  float q0sA = state[bA*14 + subc];
  float q0sB = state[bB*14 + subc];
  float dq0sA = dq0A[0], dq0sB = dq0B[0];
  #pragma unroll
  for (int k = 1; k < 7; ++k) {
    dq0sA = (subc == k) ? dq0A[k] : dq0sA;
    dq0sB = (subc == k) ? dq0B[k] : dq0sB;
  }

  float qssA = q0sA, dqssA = dq0sA, accqA = 0.0f, accdqA = 0.0f;
  float qssB = q0sB, dqssB = dq0sB, accqB = 0.0f, accdqB = 0.0f;
  float aA[7], aB[7];
  const float gm = (sub == 7) ? 1.0f : 0.0f;

  #pragma unroll 1
  for (int stage = 0; stage < 4; ++stage) {
    syncw();   // XL safe to overwrite (also publishes X7p on stage 0)
    if (sub < 7) {
      build_X(C, sub, qssA, &XL[eA][sub*12]);
      build_X(C, sub, qssB, &XL[eB][sub*12]);
    }
    syncw();

    float colA[7], colB[7];
    rnea_pass(C, &XL[eA][0], dqsA, sub, gm, colA);
    rnea_pass(C, &XL[eB][0], dqsB, sub, gm, colB);

    syncw();
    #pragma unroll
    for (int k = 0; k < 7; ++k) {
      CL[eA][k*8 + sub] = colA[k];
      CL[eB][k*8 + sub] = colB[k];
    }
    syncw();
    float MmA[7][7], rhsA[7], MmB[7][7], rhsB[7];
    #pragma unroll
    for (int i = 0; i < 7; ++i) {
      const float4* rpA = (const float4*)&CL[eA][i*8];
      float4 a0 = rpA[0], a1 = rpA[1];
      MmA[i][0]=a0.x; MmA[i][1]=a0.y; MmA[i][2]=a0.z; MmA[i][3]=a0.w;
      MmA[i][4]=a1.x; MmA[i][5]=a1.y; MmA[i][6]=a1.z;
      rhsA[i] = tauA[i] - a1.w;
      const float4* rpB = (const float4*)&CL[eB][i*8];
      float4 b0 = rpB[0], b1 = rpB[1];
      MmB[i][0]=b0.x; MmB[i][1]=b0.y; MmB[i][2]=b0.z; MmB[i][3]=b0.w;
      MmB[i][4]=b1.x; MmB[i][5]=b1.y; MmB[i][6]=b1.z;
      rhsB[i] = tauB[i] - b1.w;
    }

    solve7(MmA, rhsA, aA);
    solve7(MmB, rhsB, aB);

    float aoA = aA[0], aoB = aB[0];
    #pragma unroll
    for (int k = 1; k < 7; ++k) {
      aoA = (subc == k) ? aA[k] : aoA;
      aoB = (subc == k) ? aB[k] : aoB;
    }
    float w = (stage == 1 || stage == 2) ? 2.0f : 1.0f;
    accqA += w*dqssA;  accdqA += w*aoA;
    accqB += w*dqssB;  accdqB += w*aoB;
    if (stage < 3) {
      float cc = (stage == 2) ? 0.1f : 0.05f;
      qssA  = q0sA + cc*dqssA;
      dqssA = dq0sA + cc*aoA;
      qssB  = q0sB + cc*dqssB;
      dqssB = dq0sB + cc*aoB;
      #pragma unroll
      for (int k = 0; k < 7; ++k) {
        dqsA[k] = dq0A[k] + cc*aA[k];
        dqsB[k] = dq0B[k] + cc*aB[k];
      }
    }
  }

  const float c6 = (float)(0.1/6.0);
  const float PI_F = 3.14159265358979323846f;
  const float TWO_PI_F = 6.28318530717958647692f;
  const float INV_TWO_PI_F = 0.15915494309189535f;
  float qwA, dqwA, qwB, dqwB;
  {
    float q1 = q0sA + c6*accqA;
    float d1 = dq0sA + c6*accdqA;
    float x = q1 + PI_F;
    float n = floorf(x * INV_TWO_PI_F);
    float y = fmaf(n, -TWO_PI_F, x);
    y = (y < 0.0f) ? y + TWO_PI_F : y;
    y = (y >= TWO_PI_F) ? y - TWO_PI_F : y;
    qwA = y - PI_F;
    dqwA = fminf(fmaxf(d1, -20.0f), 20.0f);
  }
  {
    float q1 = q0sB + c6*accqB;
    float d1 = dq0sB + c6*accdqB;
    float x = q1 + PI_F;
    float n = floorf(x * INV_TWO_PI_F);
    float y = fmaf(n, -TWO_PI_F, x);
    y = (y < 0.0f) ? y + TWO_PI_F : y;
    y = (y >= TWO_PI_F) ? y - TWO_PI_F : y;
    qwB = y - PI_F;
    dqwB = fminf(fmaxf(d1, -20.0f), 20.0f);
  }
  if (sub < 7) {
    out[bA*14 + sub]     = qwA;
    out[bA*14 + 7 + sub] = dqwA;
    out[bB*14 + sub]     = qwB;
    out[bB*14 + 7 + sub] = dqwB;
  }

  // ---- FK: lane sub<7 builds L_sub = M_sub * exp6(A q) for A and B;
  //      ee needs only the translation chain. ----
  syncw();
  if (sub < 7) {
    #pragma unroll
    for (int el = 0; el < 2; ++el) {
      float qw_own = (el == 0) ? qwA : qwB;
      float Re[9], pe[3];
      exp6_dev(C.A[sub][0]*qw_own, C.A[sub][1]*qw_own, C.A[sub][2]*qw_own,
               C.A[sub][3]*qw_own, C.A[sub][4]*qw_own, C.A[sub][5]*qw_own, Re, pe);
      float L[12];
      #pragma unroll
      for (int r = 0; r < 3; ++r) {
        #pragma unroll
        for (int c = 0; c < 3; ++c)   // Mr[r][k] = MrT[k*3+r]
          L[r*3+c] = C.MrT[sub][0*3+r]*Re[0*3+c] + C.MrT[sub][1*3+r]*Re[1*3+c] + C.MrT[sub][2*3+r]*Re[2*3+c];
        L[9+r] = C.MrT[sub][0*3+r]*pe[0] + C.MrT[sub][1*3+r]*pe[1] + C.MrT[sub][2*3+r]*pe[2] + C.mp[sub][r];
      }
      float4* dst = (float4*)&XL[(el == 0) ? eA : eB][sub*12];
      dst[0] = make_float4(L[0],L[1],L[2],L[3]);
      dst[1] = make_float4(L[4],L[5],L[6],L[7]);
      dst[2] = make_float4(L[8],L[9],L[10],L[11]);
    }
  }
  syncw();
  float vA0 = C.mp[7][0], vA1 = C.mp[7][1], vA2 = C.mp[7][2];
  float vB0 = vA0, vB1 = vA1, vB2 = vA2;
  #pragma unroll
  for (int i = 6; i >= 0; --i) {
    const float4* sA = (const float4*)&XL[eA][i*12];
    float4 a0 = sA[0], a1 = sA[1], a2 = sA[2];
    float nA0 = a0.x*vA0 + a0.y*vA1 + a0.z*vA2 + a2.y;
    float nA1 = a0.w*vA0 + a1.x*vA1 + a1.y*vA2 + a2.z;
    float nA2 = a1.z*vA0 + a1.w*vA1 + a2.x*vA2 + a2.w;
    vA0 = nA0; vA1 = nA1; vA2 = nA2;
    const float4* sB = (const float4*)&XL[eB][i*12];
    float4 b0 = sB[0], b1 = sB[1], b2 = sB[2];
    float nB0 = b0.x*vB0 + b0.y*vB1 + b0.z*vB2 + b2.y;
    float nB1 = b0.w*vB0 + b1.x*vB1 + b1.y*vB2 + b2.z;
    float nB2 = b1.z*vB0 + b1.w*vB1 + b2.x*vB2 + b2.w;
    vB0 = nB0; vB1 = nB1; vB2 = nB2;
  }
  {
    float evA = vA0, evB = vB0;
    evA = (sub == 1) ? vA1 : evA;  evB = (sub == 1) ? vB1 : evB;
    evA = (sub == 2) ? vA2 : evA;  evB = (sub == 2) ? vB2 : evB;
    if (sub < 3) {
      out[NB*14 + bA*3 + sub] = evA;
      out[NB*14 + bB*3 + sub] = evB;
    }
  }
}

extern "C" void kernel_launch(void* const* d_in, const int* in_sizes, int n_in,
                              void* d_out, int out_size, void* d_ws, size_t ws_size,
                              hipStream_t stream) {
  const float* state  = (const float*)d_in[0];
  const float* torque = (const float*)d_in[1];
  const float* Mp     = (const float*)d_in[2];
  const float* Ain    = (const float*)d_in[3];
  const float* Gp     = (const float*)d_in[4];
  const float* grav   = (const float*)d_in[5];
  const float* ftip   = (const float*)d_in[6];
  float* out = (float*)d_out;
  hipLaunchKernelGGL(arm_kernel, dim3(NB/16), dim3(64), 0, stream,
                     state, torque, Mp, Ain, Gp, grav, ftip, out);
}

// Round 8
// 27.583 us; speedup vs baseline: 1.2559x; 1.2244x over previous
//
#include <hip/hip_runtime.h>
#include <math.h>

#define NB 16384

// Batch-independent constants staged in LDS (uniform broadcast reads).
struct SConsts {
  float MrT[8][9];  // transpose of Mlist[i][:3,:3], row-major
  float mp[8][3];   // Mlist[i][:3,3]
  float A[7][6];    // screw axes
  float Gd[7][6];   // [Ixx,Iyy,Izz,m,m,m]
  float X7p[3];     // p of adjoint(trans_inv(Mlist[7])); its R is MrT[7]
  float g[3];
  float ftip[6];
};

// Block = 64 threads = ONE wave; cross-lane LDS deps within a wave are
// satisfied by LDS program order (validated r3-r6). Compile-time fence only.
__device__ __forceinline__ void syncw() {
  __builtin_amdgcn_sched_barrier(0);
  __builtin_amdgcn_wave_barrier();
  __builtin_amdgcn_sched_barrier(0);
}

__device__ __forceinline__ float dot6(const float* a, const float* b) {
  return a[0]*b[0]+a[1]*b[1]+a[2]*b[2]+a[3]*b[3]+a[4]*b[4]+a[5]*b[5];
}

// exp6 with native sin/cos/sqrt/rcp (1-2 ulp; threshold 0.4 >> effect).
__device__ __forceinline__ void exp6_dev(float wx, float wy, float wz,
                                         float vx, float vy, float vz,
                                         float R[9], float p[3]) {
  float th2 = wx*wx + wy*wy + wz*wz;
  float th  = __builtin_amdgcn_sqrtf(th2);
  bool sm = th < 1e-10f;
  float ths = sm ? 1.0f : th;
  float inv = __builtin_amdgcn_rcpf(ths);
  float ux = wx*inv, uy = wy*inv, uz = wz*inv;
  float s = __sinf(th);
  float c = __cosf(th);
  float omc = 1.0f - c;
  float r00 = c + omc*ux*ux;
  float r01 = omc*ux*uy - s*uz;
  float r02 = omc*ux*uz + s*uy;
  float r10 = omc*uy*ux + s*uz;
  float r11 = c + omc*uy*uy;
  float r12 = omc*uy*uz - s*ux;
  float r20 = omc*uz*ux - s*uy;
  float r21 = omc*uz*uy + s*ux;
  float r22 = c + omc*uz*uz;
  float k1 = omc*inv, k2 = (th - s)*inv;
  float cx = uy*vz - uz*vy, cy = uz*vx - ux*vz, cz = ux*vy - uy*vx;
  float udv = ux*vx + uy*vy + uz*vz;
  float px = vx + k1*cx + k2*(ux*udv - vx);
  float py = vy + k1*cy + k2*(uy*udv - vy);
  float pz = vz + k1*cz + k2*(uz*udv - vz);
  R[0]=sm?1.f:r00; R[1]=sm?0.f:r01; R[2]=sm?0.f:r02;
  R[3]=sm?0.f:r10; R[4]=sm?1.f:r11; R[5]=sm?0.f:r12;
  R[6]=sm?0.f:r20; R[7]=sm?0.f:r21; R[8]=sm?1.f:r22;
  p[0]=sm?vx:px; p[1]=sm?vy:py; p[2]=sm?vz:pz;
}

// Adjoint apply: out = Ad(R,p) * in, in = (w,v). top = Rw; bot = p x (Rw) + Rv.
__device__ __forceinline__ void Xapply(const float* R, const float* p,
                                       const float in[6], float out[6]) {
  float a = R[0]*in[0]+R[1]*in[1]+R[2]*in[2];
  float b = R[3]*in[0]+R[4]*in[1]+R[5]*in[2];
  float c = R[6]*in[0]+R[7]*in[1]+R[8]*in[2];
  float d = R[0]*in[3]+R[1]*in[4]+R[2]*in[5];
  float e = R[3]*in[3]+R[4]*in[4]+R[5]*in[5];
  float f = R[6]*in[3]+R[7]*in[4]+R[8]*in[5];
  out[0]=a; out[1]=b; out[2]=c;
  out[3] = p[1]*c - p[2]*b + d;
  out[4] = p[2]*a - p[0]*c + e;
  out[5] = p[0]*b - p[1]*a + f;
}

// Adjoint-transpose apply: in = (m,f). top = R^T (m - p x f); bot = R^T f.
__device__ __forceinline__ void XTapply(const float* R, const float* p,
                                        const float in[6], float out[6]) {
  float fx=in[3], fy=in[4], fz=in[5];
  float tx = in[0] - (p[1]*fz - p[2]*fy);
  float ty = in[1] - (p[2]*fx - p[0]*fz);
  float tz = in[2] - (p[0]*fy - p[1]*fx);
  out[0] = R[0]*tx + R[3]*ty + R[6]*tz;
  out[1] = R[1]*tx + R[4]*ty + R[7]*tz;
  out[2] = R[2]*tx + R[5]*ty + R[8]*tz;
  out[3] = R[0]*fx + R[3]*fy + R[6]*fz;
  out[4] = R[1]*fx + R[4]*fy + R[7]*fz;
  out[5] = R[2]*fx + R[5]*fy + R[8]*fz;
}

// 8 lanes per element. Roles sub=0..6: mass-matrix column j=sub (dq=0, ddq=e_j,
// g=0, ftip=0). Role sub=7: bias torque h (real dq, ddq=0, real g, ftip).
// Solve is shuffle-distributed: M symmetric -> lane j's col[] IS row j.
extern "C" __global__ void __launch_bounds__(64, 2)
arm_kernel(const float* __restrict__ state, const float* __restrict__ torque,
           const float* __restrict__ Mp, const float* __restrict__ Ain,
           const float* __restrict__ Gp, const float* __restrict__ grav,
           const float* __restrict__ ftip_in, float* __restrict__ out)
{
  __shared__ SConsts C;
  __shared__ float XL[8][100];  // per element: 7 joints x (R 9 + p 3); stride 100
  const int t = threadIdx.x;

  // Desync co-resident waves so one fills the other's stall bubbles.
  // s_sleep needs a LITERAL operand -> switch over constant variants.
  switch (blockIdx.x & 3) {
    case 1: __builtin_amdgcn_s_sleep(2); break;
    case 2: __builtin_amdgcn_s_sleep(4); break;
    case 3: __builtin_amdgcn_s_sleep(6); break;
    default: break;
  }

  // Cooperative constant staging.
  {
    int i = t >> 3;
    #pragma unroll
    for (int kk = (t & 7); kk < 12; kk += 8) {
      if (kk < 9) {
        int r = kk / 3, c = kk - 3*(kk/3);
        C.MrT[i][c*3 + r] = Mp[i*16 + r*4 + c];
      } else {
        int r = kk - 9;
        C.mp[i][r] = Mp[i*16 + r*4 + 3];
      }
    }
    if (t < 42) {
      int i2 = t / 6, k = t - 6*(t/6);
      C.A[i2][k] = Ain[t];
      C.Gd[i2][k] = (k < 3) ? Gp[i2*4 + k] : Gp[i2*4 + 3];
    }
    if (t < 3) C.g[t] = grav[t];
    if (t < 6) C.ftip[t] = ftip_in[t];
  }
  syncw();
  if (t < 3)
    C.X7p[t] = -(C.MrT[7][t*3+0]*C.mp[7][0] + C.MrT[7][t*3+1]*C.mp[7][1] + C.MrT[7][t*3+2]*C.mp[7][2]);
  syncw();

  const int sub = t & 7;
  const int e   = t >> 3;
  const int b   = blockIdx.x * 8 + e;
  const int subc = (sub < 7) ? sub : 6;   // clamp for lane 7's own-joint scalars

  float dq0[7], dqs[7];
  #pragma unroll
  for (int k = 0; k < 7; ++k) {
    dq0[k] = state[b*14 + 7 + k];
    dqs[k] = dq0[k];
  }
  float tau_own = torque[b*7 + subc] * 50.0f;
  float q0s  = state[b*14 + subc];
  float dq0s = dq0[0];
  #pragma unroll
  for (int k = 1; k < 7; ++k) dq0s = (subc == k) ? dq0[k] : dq0s;

  float qss = q0s, dqss = dq0s;
  float accqs = 0.0f, accdqs = 0.0f;
  float a[7];
  const float gm = (sub == 7) ? 1.0f : 0.0f;

  #pragma unroll 1
  for (int stage = 0; stage < 4; ++stage) {
    syncw();   // XL safe to overwrite (same-wave DS program order)
    if (sub < 7) {
      float Re[9], pe[3];
      exp6_dev(-C.A[sub][0]*qss, -C.A[sub][1]*qss, -C.A[sub][2]*qss,
               -C.A[sub][3]*qss, -C.A[sub][4]*qss, -C.A[sub][5]*qss, Re, pe);
      float Xr[12];
      #pragma unroll
      for (int r = 0; r < 3; ++r) {
        #pragma unroll
        for (int c = 0; c < 3; ++c)
          Xr[r*3+c] = Re[r*3+0]*C.MrT[sub][0+c] + Re[r*3+1]*C.MrT[sub][3+c] + Re[r*3+2]*C.MrT[sub][6+c];
      }
      #pragma unroll
      for (int r = 0; r < 3; ++r)
        Xr[9+r] = pe[r] - (Xr[r*3+0]*C.mp[sub][0] + Xr[r*3+1]*C.mp[sub][1] + Xr[r*3+2]*C.mp[sub][2]);
      float4* dst = (float4*)&XL[e][sub*12];
      dst[0] = make_float4(Xr[0],Xr[1],Xr[2],Xr[3]);
      dst[1] = make_float4(Xr[4],Xr[5],Xr[6],Xr[7]);
      dst[2] = make_float4(Xr[8],Xr[9],Xr[10],Xr[11]);
    }
    syncw();

    // Hoist all 7 joint transforms into registers once; reuse in fwd + bwd.
    float X[7][12];
    #pragma unroll
    for (int i = 0; i < 7; ++i) {
      const float4* sx = (const float4*)&XL[e][i*12];
      float4 x0 = sx[0], x1 = sx[1], x2 = sx[2];
      X[i][0]=x0.x; X[i][1]=x0.y; X[i][2]=x0.z; X[i][3]=x0.w;
      X[i][4]=x1.x; X[i][5]=x1.y; X[i][6]=x1.z; X[i][7]=x1.w;
      X[i][8]=x2.x; X[i][9]=x2.y; X[i][10]=x2.z; X[i][11]=x2.w;
    }

    // ---- generalized RNEA (per-role dq/ddq/g/ftip) ----
    float V[6] = {0,0,0,0,0,0};
    float Vd[6];
    Vd[0]=0.0f; Vd[1]=0.0f; Vd[2]=0.0f;
    Vd[3] = -gm*C.g[0]; Vd[4] = -gm*C.g[1]; Vd[5] = -gm*C.g[2];
    float Fb[7][6];
    #pragma unroll
    for (int i = 0; i < 7; ++i) {
      float dqi  = (sub == 7) ? dqs[i] : 0.0f;
      float ddqi = (sub == i) ? 1.0f : 0.0f;
      float tv[6];
      Xapply(X[i], X[i]+9, V, tv);
      #pragma unroll
      for (int k = 0; k < 6; ++k) V[k] = tv[k] + C.A[i][k]*dqi;
      Xapply(X[i], X[i]+9, Vd, tv);
      float wx=V[0],wy=V[1],wz=V[2],vx=V[3],vy=V[4],vz=V[5];
      float ax=C.A[i][0],ay=C.A[i][1],az=C.A[i][2];
      float bx=C.A[i][3],by=C.A[i][4],bz=C.A[i][5];
      Vd[0] = tv[0] + ax*ddqi + (wy*az - wz*ay)*dqi;
      Vd[1] = tv[1] + ay*ddqi + (wz*ax - wx*az)*dqi;
      Vd[2] = tv[2] + az*ddqi + (wx*ay - wy*ax)*dqi;
      Vd[3] = tv[3] + bx*ddqi + (vy*az - vz*ay + wy*bz - wz*by)*dqi;
      Vd[4] = tv[4] + by*ddqi + (vz*ax - vx*az + wz*bx - wx*bz)*dqi;
      Vd[5] = tv[5] + bz*ddqi + (vx*ay - vy*ax + wx*by - wy*bx)*dqi;
      float g0=C.Gd[i][0], g1=C.Gd[i][1], g2=C.Gd[i][2], m=C.Gd[i][3];
      float Gt0=g0*wx, Gt1=g1*wy, Gt2=g2*wz;
      float Gb0=m*vx,  Gb1=m*vy,  Gb2=m*vz;
      Fb[i][0] = g0*Vd[0] + (wy*Gt2 - wz*Gt1) + (vy*Gb2 - vz*Gb1);
      Fb[i][1] = g1*Vd[1] + (wz*Gt0 - wx*Gt2) + (vz*Gb0 - vx*Gb2);
      Fb[i][2] = g2*Vd[2] + (wx*Gt1 - wy*Gt0) + (vx*Gb1 - vy*Gb0);
      Fb[i][3] = m*Vd[3] + (wy*Gb2 - wz*Gb1);
      Fb[i][4] = m*Vd[4] + (wz*Gb0 - wx*Gb2);
      Fb[i][5] = m*Vd[5] + (wx*Gb1 - wy*Gb0);
    }
    float col[7];
    float F[6];
    #pragma unroll
    for (int k = 0; k < 6; ++k) F[k] = gm*C.ftip[k];
    #pragma unroll
    for (int i = 6; i >= 0; --i) {
      float tv[6];
      if (i == 6) XTapply(C.MrT[7], C.X7p, F, tv);
      else        XTapply(X[i+1], X[i+1]+9, F, tv);
      #pragma unroll
      for (int k = 0; k < 6; ++k) F[k] = tv[k] + Fb[i][k];
      col[i] = dot6(F, C.A[i]);
    }

    // ---- rhs: h lives in lane 7's col[]; pick own entry ----
    float rhs_own;
    {
      float h_own = __shfl(col[0], 7, 8);
      #pragma unroll
      for (int i = 1; i < 7; ++i) {
        float hi = __shfl(col[i], 7, 8);
        h_own = (subc == i) ? hi : h_own;
      }
      rhs_own = tau_own - h_own;
    }

    // ---- distributed Gaussian elimination (no pivot; SPD). Lane j owns
    //      row j = col[] (M symmetric). Lane 7 carries garbage, never read. ----
    float row[7];
    #pragma unroll
    for (int c = 0; c < 7; ++c) row[c] = col[c];
    float invd_own = 0.0f;
    #pragma unroll
    for (int k = 0; k < 7; ++k) {
      float pk    = __shfl(row[k], k, 8);
      float prhs  = __shfl(rhs_own, k, 8);
      float invpk = __builtin_amdgcn_rcpf(pk);
      invd_own = (subc == k) ? invpk : invd_own;
      float f = row[k] * invpk;
      f = (sub > k) ? f : 0.0f;       // rows <= k unchanged (fma with f=0)
      #pragma unroll
      for (int c = k+1; c < 7; ++c) {
        float pc = __shfl(row[c], k, 8);
        row[c] -= f * pc;
      }
      rhs_own -= f * prhs;
    }
    // back-substitution; x_i broadcast from lane i
    #pragma unroll
    for (int i = 6; i >= 0; --i) {
      float s = rhs_own;
      #pragma unroll
      for (int c = i+1; c < 7; ++c) s -= row[c] * a[c];
      float val = s * invd_own;
      a[i] = __shfl(val, i, 8);
    }

    // ---- RK4 accumulate / advance (own-joint scalars) ----
    float a_own = a[0];
    #pragma unroll
    for (int k = 1; k < 7; ++k) a_own = (subc == k) ? a[k] : a_own;
    float w = (stage == 1 || stage == 2) ? 2.0f : 1.0f;
    accqs  += w*dqss;
    accdqs += w*a_own;
    if (stage < 3) {
      float cc = (stage == 2) ? 0.1f : 0.05f;
      qss  = q0s + cc*dqss;
      dqss = dq0s + cc*a_own;
      #pragma unroll
      for (int k = 0; k < 7; ++k) dqs[k] = dq0[k] + cc*a[k];
    }
  }

  const float c6 = (float)(0.1/6.0);
  const float PI_F = 3.14159265358979323846f;
  const float TWO_PI_F = 6.28318530717958647692f;
  const float INV_TWO_PI_F = 0.15915494309189535f;
  float q1 = q0s  + c6*accqs;
  float d1 = dq0s + c6*accdqs;
  float x = q1 + PI_F;
  float n = floorf(x * INV_TWO_PI_F);
  float y = fmaf(n, -TWO_PI_F, x);
  y = (y < 0.0f) ? y + TWO_PI_F : y;
  y = (y >= TWO_PI_F) ? y - TWO_PI_F : y;
  float qw_own  = y - PI_F;
  float dqw_own = fminf(fmaxf(d1, -20.0f), 20.0f);
  if (sub < 7) {
    out[b*14 + sub]     = qw_own;
    out[b*14 + 7 + sub] = dqw_own;
  }

  // ---- FK: lane sub<7 builds L_sub = M_sub * exp6(A q); translation chain. ----
  syncw();
  if (sub < 7) {
    float Re[9], pe[3];
    exp6_dev(C.A[sub][0]*qw_own, C.A[sub][1]*qw_own, C.A[sub][2]*qw_own,
             C.A[sub][3]*qw_own, C.A[sub][4]*qw_own, C.A[sub][5]*qw_own, Re, pe);
    float L[12];
    #pragma unroll
    for (int r = 0; r < 3; ++r) {
      #pragma unroll
      for (int c = 0; c < 3; ++c)   // Mr[r][k] = MrT[k*3+r]
        L[r*3+c] = C.MrT[sub][0*3+r]*Re[0*3+c] + C.MrT[sub][1*3+r]*Re[1*3+c] + C.MrT[sub][2*3+r]*Re[2*3+c];
      L[9+r] = C.MrT[sub][0*3+r]*pe[0] + C.MrT[sub][1*3+r]*pe[1] + C.MrT[sub][2*3+r]*pe[2] + C.mp[sub][r];
    }
    float4* dst = (float4*)&XL[e][sub*12];
    dst[0] = make_float4(L[0],L[1],L[2],L[3]);
    dst[1] = make_float4(L[4],L[5],L[6],L[7]);
    dst[2] = make_float4(L[8],L[9],L[10],L[11]);
  }
  syncw();
  float v0 = C.mp[7][0], v1 = C.mp[7][1], v2 = C.mp[7][2];
  #pragma unroll
  for (int i = 6; i >= 0; --i) {
    const float4* sx = (const float4*)&XL[e][i*12];
    float4 x0 = sx[0], x1 = sx[1], x2 = sx[2];
    float n0 = x0.x*v0 + x0.y*v1 + x0.z*v2 + x2.y;
    float n1 = x0.w*v0 + x1.x*v1 + x1.y*v2 + x2.z;
    float n2 = x1.z*v0 + x1.w*v1 + x2.x*v2 + x2.w;
    v0 = n0; v1 = n1; v2 = n2;
  }
  {
    float ev = v0;
    ev = (sub == 1) ? v1 : ev;
    ev = (sub == 2) ? v2 : ev;
    if (sub < 3) out[NB*14 + b*3 + sub] = ev;
  }
}

extern "C" void kernel_launch(void* const* d_in, const int* in_sizes, int n_in,
                              void* d_out, int out_size, void* d_ws, size_t ws_size,
                              hipStream_t stream) {
  const float* state  = (const float*)d_in[0];
  const float* torque = (const float*)d_in[1];
  const float* Mp     = (const float*)d_in[2];
  const float* Ain    = (const float*)d_in[3];
  const float* Gp     = (const float*)d_in[4];
  const float* grav   = (const float*)d_in[5];
  const float* ftip   = (const float*)d_in[6];
  float* out = (float*)d_out;
  hipLaunchKernelGGL(arm_kernel, dim3(NB/8), dim3(64), 0, stream,
                     state, torque, Mp, Ain, Gp, grav, ftip, out);
}